// Round 1
// baseline (2902.887 us; speedup 1.0000x reference)
//
#include <hip/hip_runtime.h>
#include <cfloat>

// Problem constants (B=8, S=2048, D=256, K=8192)
#define N_TOK 16384
#define DIM 256
#define KCB 8192
#define BETA_C 0.25f

// Tiling
#define BR 64    // rows per block
#define BK 64    // codes / out-cols per k-tile
#define DC 64    // d-chunk staged in LDS
#define LSTR 66  // LDS row stride (floats): conflict-free + 8B-aligned float2

// ---------------- codebook row norms ----------------
__global__ void enorm_kernel(const float* __restrict__ emb, float* __restrict__ enorm) {
    const int wid = threadIdx.x >> 6, lane = threadIdx.x & 63;
    const int k = blockIdx.x * 4 + wid;
    const float* row = emb + (size_t)k * DIM;
    float s = 0.f;
#pragma unroll
    for (int i = 0; i < 4; ++i) { const float v = row[lane + 64 * i]; s += v * v; }
#pragma unroll
    for (int o = 32; o > 0; o >>= 1) s += __shfl_down(s, o, 64);
    if (lane == 0) enorm[k] = s;
}

// ---------------- distance + argmin ----------------
// Block: 64 rows x all 8192 codes. dist = ||e||^2 - 2*x.e  (+||x||^2 added in loss only)
__global__ void __launch_bounds__(256)
dist_argmin_kernel(const float* __restrict__ x, const float* __restrict__ emb,
                   const float* __restrict__ enorm, int* __restrict__ idx_out,
                   float* __restrict__ minq_out) {
    __shared__ float xs[BR][LSTR];
    __shared__ float es[BK][LSTR];
    __shared__ float enormS[BK];
    __shared__ float rv[BR][16];
    __shared__ int   ri[BR][16];

    const int tid = threadIdx.x;
    const int ty = tid >> 4, tx = tid & 15;
    const int row0 = blockIdx.x * BR;

    float bestv[4];
    int   besti[4];
#pragma unroll
    for (int a = 0; a < 4; ++a) { bestv[a] = FLT_MAX; besti[a] = 0; }

    for (int kt = 0; kt < KCB / BK; ++kt) {
        const int k0 = kt * BK;
        float acc[4][4];
#pragma unroll
        for (int a = 0; a < 4; ++a)
#pragma unroll
            for (int b = 0; b < 4; ++b) acc[a][b] = 0.f;

        __syncthreads();   // guard enormS/xs/es against previous iteration readers
        if (tid < BK) enormS[tid] = enorm[k0 + tid];

        for (int dc = 0; dc < DIM / DC; ++dc) {
            __syncthreads();
            // stage 64x64 chunks of x and e (coalesced float4 global reads)
#pragma unroll
            for (int i = 0; i < 4; ++i) {
                const int f = tid + 256 * i;   // 0..1023 float4 slots
                const int r = f >> 4;          // 16 float4 per row
                const int c4 = f & 15;
                const float4 xv = *reinterpret_cast<const float4*>(
                    x + (size_t)(row0 + r) * DIM + dc * DC + c4 * 4);
                float* dx = &xs[r][c4 * 4];
                reinterpret_cast<float2*>(dx)[0] = make_float2(xv.x, xv.y);
                reinterpret_cast<float2*>(dx)[1] = make_float2(xv.z, xv.w);
                const float4 ev = *reinterpret_cast<const float4*>(
                    emb + (size_t)(k0 + r) * DIM + dc * DC + c4 * 4);
                float* de = &es[r][c4 * 4];
                reinterpret_cast<float2*>(de)[0] = make_float2(ev.x, ev.y);
                reinterpret_cast<float2*>(de)[1] = make_float2(ev.z, ev.w);
            }
            __syncthreads();
            // 4x4 register tile, float2 LDS reads (conflict-free at stride 66)
#pragma unroll
            for (int d2 = 0; d2 < DC / 2; ++d2) {
                float2 xr[4], ek[4];
#pragma unroll
                for (int j = 0; j < 4; ++j) {
                    xr[j] = reinterpret_cast<const float2*>(&xs[ty + 16 * j][0])[d2];
                    ek[j] = reinterpret_cast<const float2*>(&es[tx + 16 * j][0])[d2];
                }
#pragma unroll
                for (int a = 0; a < 4; ++a)
#pragma unroll
                    for (int b = 0; b < 4; ++b)
                        acc[a][b] += xr[a].x * ek[b].x + xr[a].y * ek[b].y;
            }
        }
        // epilogue: update running argmin (strict < keeps first occurrence;
        // per-thread k's ascend across tiles)
#pragma unroll
        for (int a = 0; a < 4; ++a)
#pragma unroll
            for (int b = 0; b < 4; ++b) {
                const float v = enormS[tx + 16 * b] - 2.f * acc[a][b];
                const int kg = k0 + tx + 16 * b;
                if (v < bestv[a]) { bestv[a] = v; besti[a] = kg; }
            }
    }

    __syncthreads();
#pragma unroll
    for (int a = 0; a < 4; ++a) {
        rv[ty + 16 * a][tx] = bestv[a];
        ri[ty + 16 * a][tx] = besti[a];
    }
    __syncthreads();
    if (tid < BR) {
        float bv = rv[tid][0];
        int bi = ri[tid][0];
#pragma unroll
        for (int j = 1; j < 16; ++j) {
            const float v = rv[tid][j];
            const int bj = ri[tid][j];
            if (v < bv || (v == bv && bj < bi)) { bv = v; bi = bj; }
        }
        idx_out[row0 + tid] = bi;
        minq_out[row0 + tid] = bv;
    }
}

// ---------------- MLP layers ----------------
// MODE 1: out = relu((x - emb[idx]) @ W1 + b1)        (src = x,  out = h)
// MODE 2: out = emb[idx] + (h @ W2 + b2)              (src = h,  out = z)
template <int MODE>
__global__ void __launch_bounds__(256)
mlp_kernel(const float* __restrict__ src, const float* __restrict__ emb,
           const int* __restrict__ idx, const float* __restrict__ W,
           const float* __restrict__ bias, float* __restrict__ out) {
    __shared__ float rs[BR][LSTR];
    __shared__ float wsl[BK][LSTR];   // W^T tile: wsl[e_local][d_local]
    __shared__ int idxs[BR];

    const int tid = threadIdx.x;
    const int ty = tid >> 4, tx = tid & 15;
    const int row0 = blockIdx.x * BR;
    const int e0 = blockIdx.y * BK;

    if (tid < BR) idxs[tid] = idx[row0 + tid];

    float acc[4][4];
#pragma unroll
    for (int a = 0; a < 4; ++a)
#pragma unroll
        for (int b = 0; b < 4; ++b) acc[a][b] = 0.f;

    for (int dc = 0; dc < DIM / DC; ++dc) {
        __syncthreads();
#pragma unroll
        for (int i = 0; i < 4; ++i) {
            const int f = tid + 256 * i;
            const int r = f >> 4;      // row (src) / d_local (W)
            const int c4 = f & 15;
            float4 sv = *reinterpret_cast<const float4*>(
                src + (size_t)(row0 + r) * DIM + dc * DC + c4 * 4);
            if (MODE == 1) {
                const float4 zv = *reinterpret_cast<const float4*>(
                    emb + (size_t)idxs[r] * DIM + dc * DC + c4 * 4);
                sv.x -= zv.x; sv.y -= zv.y; sv.z -= zv.z; sv.w -= zv.w;
            }
            float* dr = &rs[r][c4 * 4];
            reinterpret_cast<float2*>(dr)[0] = make_float2(sv.x, sv.y);
            reinterpret_cast<float2*>(dr)[1] = make_float2(sv.z, sv.w);
            // transpose-stage W tile: wsl[e][d] = W[d][e]
            const int dl = r;
            const float4 wv = *reinterpret_cast<const float4*>(
                W + (size_t)(dc * DC + dl) * DIM + e0 + c4 * 4);
            wsl[c4 * 4 + 0][dl] = wv.x;
            wsl[c4 * 4 + 1][dl] = wv.y;
            wsl[c4 * 4 + 2][dl] = wv.z;
            wsl[c4 * 4 + 3][dl] = wv.w;
        }
        __syncthreads();
#pragma unroll
        for (int d2 = 0; d2 < DC / 2; ++d2) {
            float2 xr[4], wk[4];
#pragma unroll
            for (int j = 0; j < 4; ++j) {
                xr[j] = reinterpret_cast<const float2*>(&rs[ty + 16 * j][0])[d2];
                wk[j] = reinterpret_cast<const float2*>(&wsl[tx + 16 * j][0])[d2];
            }
#pragma unroll
            for (int a = 0; a < 4; ++a)
#pragma unroll
                for (int b = 0; b < 4; ++b)
                    acc[a][b] += xr[a].x * wk[b].x + xr[a].y * wk[b].y;
        }
    }

#pragma unroll
    for (int a = 0; a < 4; ++a)
#pragma unroll
        for (int b = 0; b < 4; ++b) {
            const int row_l = ty + 16 * a;
            const int e = e0 + tx + 16 * b;
            float v = acc[a][b] + bias[e];
            if (MODE == 1) {
                v = fmaxf(v, 0.f);
            } else {
                v += emb[(size_t)idxs[row_l] * DIM + e];
            }
            out[(size_t)(row0 + row_l) * DIM + e] = v;
        }
}

// ---------------- loss ----------------
__global__ void loss_partial_kernel(const float* __restrict__ x, float* __restrict__ partial) {
    const int tid = threadIdx.x;
    float s = 0.f;
    const int total4 = N_TOK * DIM / 4;
    for (int i = blockIdx.x * blockDim.x + tid; i < total4; i += gridDim.x * blockDim.x) {
        const float4 v = reinterpret_cast<const float4*>(x)[i];
        s += v.x * v.x + v.y * v.y + v.z * v.z + v.w * v.w;
    }
#pragma unroll
    for (int o = 32; o > 0; o >>= 1) s += __shfl_down(s, o, 64);
    __shared__ float sb[4];
    const int wid = tid >> 6, lane = tid & 63;
    if (lane == 0) sb[wid] = s;
    __syncthreads();
    if (tid == 0) partial[blockIdx.x] = sb[0] + sb[1] + sb[2] + sb[3];
}

__global__ void loss_final_kernel(const float* __restrict__ minq,
                                  const float* __restrict__ partial,
                                  float* __restrict__ loss_out) {
    const int tid = threadIdx.x;
    float s = 0.f;
    for (int i = tid; i < N_TOK; i += 256) s += minq[i];
    s += partial[tid];   // 256 block partials of sum(x^2)
#pragma unroll
    for (int o = 32; o > 0; o >>= 1) s += __shfl_down(s, o, 64);
    __shared__ float sb[4];
    const int wid = tid >> 6, lane = tid & 63;
    if (lane == 0) sb[wid] = s;
    __syncthreads();
    if (tid == 0) loss_out[0] = BETA_C * ((sb[0] + sb[1] + sb[2] + sb[3]) / (float)N_TOK);
}

extern "C" void kernel_launch(void* const* d_in, const int* in_sizes, int n_in,
                              void* d_out, int out_size, void* d_ws, size_t ws_size,
                              hipStream_t stream) {
    const float* x   = (const float*)d_in[0];
    const float* emb = (const float*)d_in[1];
    const float* W1  = (const float*)d_in[2];
    const float* b1  = (const float*)d_in[3];
    const float* W2  = (const float*)d_in[4];
    const float* b2  = (const float*)d_in[5];

    float* z_out = (float*)d_out;                       // N_TOK*DIM floats
    float* loss_out = z_out + (size_t)N_TOK * DIM;      // 1 float

    // workspace layout (needs ~17.1 MB)
    char* ws = (char*)d_ws;
    float* enorm   = (float*)(ws);               // 8192 f
    int*   idxb    = (int*)(ws + 32768);         // 16384 i
    float* minq    = (float*)(ws + 98304);       // 16384 f
    float* partial = (float*)(ws + 163840);      // 256 f
    float* h       = (float*)(ws + 262144);      // 16384*256 f (16 MB)

    hipLaunchKernelGGL(enorm_kernel, dim3(KCB / 4), dim3(256), 0, stream, emb, enorm);
    hipLaunchKernelGGL(dist_argmin_kernel, dim3(N_TOK / BR), dim3(256), 0, stream,
                       x, emb, enorm, idxb, minq);
    hipLaunchKernelGGL((mlp_kernel<1>), dim3(N_TOK / BR, DIM / BK), dim3(256), 0, stream,
                       x, emb, idxb, W1, b1, h);
    hipLaunchKernelGGL((mlp_kernel<2>), dim3(N_TOK / BR, DIM / BK), dim3(256), 0, stream,
                       h, emb, idxb, W2, b2, z_out);
    hipLaunchKernelGGL(loss_partial_kernel, dim3(256), dim3(256), 0, stream, x, partial);
    hipLaunchKernelGGL(loss_final_kernel, dim3(1), dim3(256), 0, stream, minq, partial, loss_out);
}

// Round 2
// 511.400 us; speedup vs baseline: 5.6764x; 5.6764x over previous
//
#include <hip/hip_runtime.h>
#include <cfloat>

// Problem constants (B=8, S=2048, D=256, K=8192)
#define N_TOK 16384
#define DIM 256
#define KCB 8192
#define BETA_C 0.25f

typedef __attribute__((ext_vector_type(8))) short short8;   // 8 bf16 (4 VGPRs)
typedef __attribute__((ext_vector_type(4))) float f32x4;    // MFMA acc

// Swizzled byte offset within a [128 rows][64 bf16] tile (128 B rows).
// XOR of bits 4-6 with row&7 kills the 16-way bank conflict on frag reads.
__device__ __forceinline__ int swz(int row, int byte_in_row) {
    return row * 128 + (byte_in_row ^ ((row & 7) << 4));
}

// Truncation split of 8 consecutive f32 into bf16 hi/lo planes.
// hi = trunc_bf16(v); lo = trunc_bf16(v - hi).  Residual ~2^-16|v| per elem,
// far below the top-2 rescore safety margin.
__device__ __forceinline__ void cvt8(const float* __restrict__ p, short8& hi, short8& lo) {
    const float4 a = *reinterpret_cast<const float4*>(p);
    const float4 b = *reinterpret_cast<const float4*>(p + 4);
    float vv[8] = {a.x, a.y, a.z, a.w, b.x, b.y, b.z, b.w};
#pragma unroll
    for (int j = 0; j < 8; ++j) {
        const float v = vv[j];
        const unsigned u = __float_as_uint(v);
        const float hf = __uint_as_float(u & 0xFFFF0000u);
        const float lf = v - hf;
        hi[j] = (short)(u >> 16);
        lo[j] = (short)(__float_as_uint(lf) >> 16);
    }
}

// ---------------- codebook row norms ----------------
__global__ void enorm_kernel(const float* __restrict__ emb, float* __restrict__ enorm) {
    const int wid = threadIdx.x >> 6, lane = threadIdx.x & 63;
    const int k = blockIdx.x * 4 + wid;
    const float* row = emb + (size_t)k * DIM;
    float s = 0.f;
#pragma unroll
    for (int i = 0; i < 4; ++i) { const float v = row[lane + 64 * i]; s += v * v; }
#pragma unroll
    for (int o = 32; o > 0; o >>= 1) s += __shfl_down(s, o, 64);
    if (lane == 0) enorm[k] = s;
}

// ---------------- MFMA distance + per-split top-2 ----------------
// Block: 128 rows x 128 codes/tile, sweeping 2048 codes (K-split blockIdx.y).
// dist = ||e||^2 - 2*x.e  (row-constant ||x||^2 irrelevant for argmin).
// 3-pass bf16-split MFMA; per-row top-2 (value,index) written per split.
__global__ void __launch_bounds__(256, 2)
dist_topk_kernel(const float* __restrict__ x, const float* __restrict__ emb,
                 const float* __restrict__ enorm, uint4* __restrict__ split_out) {
    __shared__ unsigned short smem[32768];  // 64 KiB: xh|xl|eh|el tiles, 16 KiB each
    char* sb = (char*)smem;

    const int tid = threadIdx.x;
    const int lane = tid & 63;
    const int w = tid >> 6;               // wave 0..3
    const int wy = w >> 1, wx = w & 1;    // 2x2 wave grid, 64x64 tiles
    const int row0 = blockIdx.x * 128;
    const int c_base = blockIdx.y * 2048;
    const int l15 = lane & 15, l4 = lane >> 4;

    // per-lane top-2 state for 16 row-slots (rows m*16 + l4*4 + j)
    float tv1[16], tv2[16];
    int ti1[16], ti2[16];
#pragma unroll
    for (int s = 0; s < 16; ++s) { tv1[s] = FLT_MAX; tv2[s] = FLT_MAX; ti1[s] = 0; ti2[s] = 0; }

    for (int kt = 0; kt < 16; ++kt) {
        const int k0 = c_base + kt * 128;
        f32x4 acc[4][4];
#pragma unroll
        for (int m = 0; m < 4; ++m)
#pragma unroll
            for (int n = 0; n < 4; ++n) {
                f32x4 z = {0.f, 0.f, 0.f, 0.f};
                acc[m][n] = z;
            }

        for (int dc = 0; dc < 4; ++dc) {
            __syncthreads();   // protect LDS against previous chunk's readers
            // stage x-tile [128][64] and e-tile [128][64], hi/lo split, swizzled
#pragma unroll
            for (int i = 0; i < 4; ++i) {
                const int s_ = tid + 256 * i;       // 0..1023 write slots
                const int r = s_ >> 3, sl = s_ & 7; // row, 8-elem slot
                const int woff = swz(r, sl * 16);
                short8 hi, lo;
                cvt8(x + (size_t)(row0 + r) * DIM + dc * 64 + sl * 8, hi, lo);
                *reinterpret_cast<short8*>(sb + woff) = hi;
                *reinterpret_cast<short8*>(sb + 16384 + woff) = lo;
                cvt8(emb + (size_t)(k0 + r) * DIM + dc * 64 + sl * 8, hi, lo);
                *reinterpret_cast<short8*>(sb + 32768 + woff) = hi;
                *reinterpret_cast<short8*>(sb + 49152 + woff) = lo;
            }
            __syncthreads();
#pragma unroll
            for (int ks = 0; ks < 2; ++ks) {
                short8 ah[4], al[4], bh[4], bl[4];
#pragma unroll
                for (int m = 0; m < 4; ++m) {
                    const int r = wy * 64 + m * 16 + l15;
                    const int off = swz(r, ks * 64 + l4 * 16);
                    ah[m] = *reinterpret_cast<const short8*>(sb + off);
                    al[m] = *reinterpret_cast<const short8*>(sb + 16384 + off);
                }
#pragma unroll
                for (int n = 0; n < 4; ++n) {
                    const int r = wx * 64 + n * 16 + l15;
                    const int off = swz(r, ks * 64 + l4 * 16);
                    bh[n] = *reinterpret_cast<const short8*>(sb + 32768 + off);
                    bl[n] = *reinterpret_cast<const short8*>(sb + 49152 + off);
                }
#pragma unroll
                for (int m = 0; m < 4; ++m)
#pragma unroll
                    for (int n = 0; n < 4; ++n) {
                        acc[m][n] = __builtin_amdgcn_mfma_f32_16x16x32_bf16(ah[m], bh[n], acc[m][n], 0, 0, 0);
                        acc[m][n] = __builtin_amdgcn_mfma_f32_16x16x32_bf16(ah[m], bl[n], acc[m][n], 0, 0, 0);
                        acc[m][n] = __builtin_amdgcn_mfma_f32_16x16x32_bf16(al[m], bh[n], acc[m][n], 0, 0, 0);
                    }
            }
        }
        // epilogue: dist = enorm - 2*dot; update per-row top-2
#pragma unroll
        for (int n = 0; n < 4; ++n) {
            const int kg = k0 + wx * 64 + n * 16 + l15;
            const float en = enorm[kg];
#pragma unroll
            for (int m = 0; m < 4; ++m)
#pragma unroll
                for (int j = 0; j < 4; ++j) {
                    const float v = fmaf(-2.f, acc[m][n][j], en);
                    const int s = m * 4 + j;
                    if (v < tv1[s]) {
                        tv2[s] = tv1[s]; ti2[s] = ti1[s];
                        tv1[s] = v; ti1[s] = kg;
                    } else if (v < tv2[s]) {
                        tv2[s] = v; ti2[s] = kg;
                    }
                }
        }
    }

    // block-level merge: 32 contributors per row -> top-2, via LDS (aliased)
    __syncthreads();
    uint4* sc = reinterpret_cast<uint4*>(sb);   // [256 threads][16 slots], 64 KiB
#pragma unroll
    for (int s = 0; s < 16; ++s)
        sc[tid * 16 + s] = make_uint4(__float_as_uint(tv1[s]), (unsigned)ti1[s],
                                      __float_as_uint(tv2[s]), (unsigned)ti2[s]);
    __syncthreads();
    if (tid < 128) {
        const int r = tid;
        const int wy2 = r >> 6, lr = r & 63;
        const int m = lr >> 4, g = (lr & 15) >> 2, j = lr & 3, s = m * 4 + j;
        float v1 = FLT_MAX, v2 = FLT_MAX;
        int i1 = 0, i2 = 0;
        for (int wx2 = 0; wx2 < 2; ++wx2)
            for (int c = 0; c < 16; ++c) {
                const uint4 q = sc[(size_t)(((wy2 * 2 + wx2) * 64 + g * 16 + c) * 16 + s)];
                const float a1 = __uint_as_float(q.x), a2 = __uint_as_float(q.z);
                if (a1 < v1) {
                    if (a2 < v1) { v1 = a1; i1 = (int)q.y; v2 = a2; i2 = (int)q.w; }
                    else { v2 = v1; i2 = i1; v1 = a1; i1 = (int)q.y; }
                } else if (a1 < v2) { v2 = a1; i2 = (int)q.y; }
            }
        split_out[(size_t)blockIdx.y * N_TOK + row0 + r] =
            make_uint4(__float_as_uint(v1), (unsigned)i1, __float_as_uint(v2), (unsigned)i2);
    }
}

// ---------------- exact f32 rescore of candidates ----------------
// One wave per row: exact ||x - e||^2 for the 8 split candidates; argmin with
// first-occurrence (lowest-index) tie-break; also emits exact min dist (loss).
__global__ void __launch_bounds__(256)
fixup_kernel(const float* __restrict__ x, const float* __restrict__ emb,
             const uint4* __restrict__ split_out, int* __restrict__ idx_out,
             float* __restrict__ minq) {
    const int w = threadIdx.x >> 6, lane = threadIdx.x & 63;
    const int n = blockIdx.x * 4 + w;
    const float4 xv = *reinterpret_cast<const float4*>(x + (size_t)n * DIM + lane * 4);
    float bestv = FLT_MAX;
    int bestk = 0x7fffffff;
    for (int sp = 0; sp < 4; ++sp) {
        const uint4 q = split_out[(size_t)sp * N_TOK + n];
        const int kc[2] = {(int)q.y, (int)q.w};
#pragma unroll
        for (int c = 0; c < 2; ++c) {
            const int k = kc[c];
            const float4 ev = *reinterpret_cast<const float4*>(emb + (size_t)k * DIM + lane * 4);
            const float dx = xv.x - ev.x, dy = xv.y - ev.y, dz = xv.z - ev.z, dw = xv.w - ev.w;
            float s = dx * dx + dy * dy + dz * dz + dw * dw;
#pragma unroll
            for (int o = 32; o > 0; o >>= 1) s += __shfl_xor(s, o, 64);
            if (s < bestv || (s == bestv && k < bestk)) { bestv = s; bestk = k; }
        }
    }
    if (lane == 0) { idx_out[n] = bestk; minq[n] = bestv; }
}

// ---------------- MLP layers (unchanged from R1, proven) ----------------
#define BR 64
#define BK 64
#define DC 64
#define LSTR 66
template <int MODE>
__global__ void __launch_bounds__(256)
mlp_kernel(const float* __restrict__ src, const float* __restrict__ emb,
           const int* __restrict__ idx, const float* __restrict__ W,
           const float* __restrict__ bias, float* __restrict__ out) {
    __shared__ float rs[BR][LSTR];
    __shared__ float wsl[BK][LSTR];
    __shared__ int idxs[BR];

    const int tid = threadIdx.x;
    const int ty = tid >> 4, tx = tid & 15;
    const int row0 = blockIdx.x * BR;
    const int e0 = blockIdx.y * BK;

    if (tid < BR) idxs[tid] = idx[row0 + tid];

    float acc[4][4];
#pragma unroll
    for (int a = 0; a < 4; ++a)
#pragma unroll
        for (int b = 0; b < 4; ++b) acc[a][b] = 0.f;

    for (int dc = 0; dc < DIM / DC; ++dc) {
        __syncthreads();
#pragma unroll
        for (int i = 0; i < 4; ++i) {
            const int f = tid + 256 * i;
            const int r = f >> 4;
            const int c4 = f & 15;
            float4 sv = *reinterpret_cast<const float4*>(
                src + (size_t)(row0 + r) * DIM + dc * DC + c4 * 4);
            if (MODE == 1) {
                const float4 zv = *reinterpret_cast<const float4*>(
                    emb + (size_t)idxs[r] * DIM + dc * DC + c4 * 4);
                sv.x -= zv.x; sv.y -= zv.y; sv.z -= zv.z; sv.w -= zv.w;
            }
            float* dr = &rs[r][c4 * 4];
            reinterpret_cast<float2*>(dr)[0] = make_float2(sv.x, sv.y);
            reinterpret_cast<float2*>(dr)[1] = make_float2(sv.z, sv.w);
            const int dl = r;
            const float4 wv = *reinterpret_cast<const float4*>(
                W + (size_t)(dc * DC + dl) * DIM + e0 + c4 * 4);
            wsl[c4 * 4 + 0][dl] = wv.x;
            wsl[c4 * 4 + 1][dl] = wv.y;
            wsl[c4 * 4 + 2][dl] = wv.z;
            wsl[c4 * 4 + 3][dl] = wv.w;
        }
        __syncthreads();
#pragma unroll
        for (int d2 = 0; d2 < DC / 2; ++d2) {
            float2 xr[4], wk[4];
#pragma unroll
            for (int jj = 0; jj < 4; ++jj) {
                xr[jj] = reinterpret_cast<const float2*>(&rs[ty + 16 * jj][0])[d2];
                wk[jj] = reinterpret_cast<const float2*>(&wsl[tx + 16 * jj][0])[d2];
            }
#pragma unroll
            for (int a = 0; a < 4; ++a)
#pragma unroll
                for (int b = 0; b < 4; ++b)
                    acc[a][b] += xr[a].x * wk[b].x + xr[a].y * wk[b].y;
        }
    }

#pragma unroll
    for (int a = 0; a < 4; ++a)
#pragma unroll
        for (int b = 0; b < 4; ++b) {
            const int row_l = ty + 16 * a;
            const int e = e0 + tx + 16 * b;
            float v = acc[a][b] + bias[e];
            if (MODE == 1) {
                v = fmaxf(v, 0.f);
            } else {
                v += emb[(size_t)idxs[row_l] * DIM + e];
            }
            out[(size_t)(row0 + row_l) * DIM + e] = v;
        }
}

// ---------------- loss: BETA * mean(exact min dist) ----------------
__global__ void loss_kernel(const float* __restrict__ minq, float* __restrict__ loss_out) {
    const int tid = threadIdx.x;
    float s = 0.f;
    for (int i = tid; i < N_TOK; i += 256) s += minq[i];
#pragma unroll
    for (int o = 32; o > 0; o >>= 1) s += __shfl_down(s, o, 64);
    __shared__ float sb[4];
    if ((tid & 63) == 0) sb[tid >> 6] = s;
    __syncthreads();
    if (tid == 0) loss_out[0] = BETA_C * ((sb[0] + sb[1] + sb[2] + sb[3]) / (float)N_TOK);
}

extern "C" void kernel_launch(void* const* d_in, const int* in_sizes, int n_in,
                              void* d_out, int out_size, void* d_ws, size_t ws_size,
                              hipStream_t stream) {
    const float* x   = (const float*)d_in[0];
    const float* emb = (const float*)d_in[1];
    const float* W1  = (const float*)d_in[2];
    const float* b1  = (const float*)d_in[3];
    const float* W2  = (const float*)d_in[4];
    const float* b2  = (const float*)d_in[5];

    float* z_out = (float*)d_out;
    float* loss_out = z_out + (size_t)N_TOK * DIM;

    // workspace (total 17,039,360 B — same footprint as the proven R1 layout):
    //   [0,32K)      enorm
    //   [32K,96K)    idx
    //   [96K,160K)   minq
    //   [256K, +1M)  split_out  (dist->fixup lifetime)
    //   [256K, +16M) h          (mlp1->mlp2 lifetime; aliases split_out safely)
    char* ws = (char*)d_ws;
    float* enorm = (float*)(ws);
    int*   idxb  = (int*)(ws + 32768);
    float* minq  = (float*)(ws + 98304);
    uint4* split_out = (uint4*)(ws + 262144);
    float* h     = (float*)(ws + 262144);

    hipLaunchKernelGGL(enorm_kernel, dim3(KCB / 4), dim3(256), 0, stream, emb, enorm);
    hipLaunchKernelGGL(dist_topk_kernel, dim3(N_TOK / 128, 4), dim3(256), 0, stream,
                       x, emb, enorm, split_out);
    hipLaunchKernelGGL(fixup_kernel, dim3(N_TOK / 4), dim3(256), 0, stream,
                       x, emb, split_out, idxb, minq);
    hipLaunchKernelGGL((mlp_kernel<1>), dim3(N_TOK / BR, DIM / BK), dim3(256), 0, stream,
                       x, emb, idxb, W1, b1, h);
    hipLaunchKernelGGL((mlp_kernel<2>), dim3(N_TOK / BR, DIM / BK), dim3(256), 0, stream,
                       h, emb, idxb, W2, b2, z_out);
    hipLaunchKernelGGL(loss_kernel, dim3(1), dim3(256), 0, stream, minq, loss_out);
}